// Round 1
// baseline (401.579 us; speedup 1.0000x reference)
//
#include <hip/hip_runtime.h>

typedef __bf16 bf16;
typedef bf16 bf16x8 __attribute__((ext_vector_type(8)));
typedef bf16 bf16x4 __attribute__((ext_vector_type(4)));
typedef float f32x4 __attribute__((ext_vector_type(4)));

#define MFMA(a, b, c) __builtin_amdgcn_mfma_f32_16x16x32_bf16((a), (b), (c), 0, 0, 0)

// Problem constants
// N=32, BSZ=512, NE=7, DIN=512, DH=256 ; M = N*BSZ*NE = 114688 rows
// out: marginal [32,512,7] = 114688 floats, joint [32,512,128] = 2097152 floats

// ---------------------------------------------------------------------------
// prep: pack W0^T, W1^T, W2^T into MFMA A-fragment order (bf16).
// A-frag layout (16x16x32): lane l holds A[m = tile*16 + (l&15)][k = kstep*32 + (l>>4)*8 + j]
// ---------------------------------------------------------------------------
__global__ __launch_bounds__(256) void k_prep(const float* __restrict__ W0,
                                              const float* __restrict__ W1,
                                              const float* __restrict__ W2,
                                              bf16* __restrict__ W0f,
                                              bf16* __restrict__ W1f,
                                              bf16* __restrict__ W2f) {
  int g = blockIdx.x * 256 + threadIdx.x;
  if (g < 16384) {                       // W0^T: 16 mtiles x 16 ksteps x 64 lanes
    int mt = g >> 10, ks = (g >> 6) & 15, lane = g & 63;
    int m = mt * 16 + (lane & 15);
    int kb = ks * 32 + (lane >> 4) * 8;
    bf16x8 v;
#pragma unroll
    for (int j = 0; j < 8; ++j) v[j] = (bf16)W0[(kb + j) * 256 + m];
    *(bf16x8*)&W0f[g * 8] = v;
  } else if (g < 24576) {                // W1^T: 16 mtiles x 8 ksteps x 64 lanes
    int h = g - 16384;
    int mt = h >> 9, ks = (h >> 6) & 7, lane = h & 63;
    int m = mt * 16 + (lane & 15);
    int kb = ks * 32 + (lane >> 4) * 8;
    bf16x8 v;
#pragma unroll
    for (int j = 0; j < 8; ++j) v[j] = (bf16)W1[(kb + j) * 256 + m];
    *(bf16x8*)&W1f[h * 8] = v;
  } else {                               // W2^T: 1 mtile (rows 0,1 valid) x 8 ksteps
    int h = g - 24576;
    int ks = h >> 6, lane = h & 63;
    int c = lane & 15;
    int kb = ks * 32 + (lane >> 4) * 8;
    bf16x8 v;
#pragma unroll
    for (int j = 0; j < 8; ++j) v[j] = (c < 2) ? (bf16)W2[(kb + j) * 2 + c] : (bf16)0.0f;
    *(bf16x8*)&W2f[h * 8] = v;
  }
}

// ---------------------------------------------------------------------------
// unary MLP, fully fused, transposed GEMMs:
//   D0 = W0^T(256x512) * X^T(512x64)  -> h0[m][n] in LDS (n contiguous)
//   D1 = W1^T(256x256) * h0^T         -> h1[m][n] in LDS
//   D2 = W2^T(2x256)   * h1^T         -> un[m][2] to global
// Block: 256 threads (4 waves), 64 example-rows. Wave w owns D-rows [64w,64w+64).
// ---------------------------------------------------------------------------
__global__ __launch_bounds__(256, 2) void k_unary(const float* __restrict__ input,
                                                  const bf16* __restrict__ W0f,
                                                  const bf16* __restrict__ W1f,
                                                  const bf16* __restrict__ W2f,
                                                  const float* __restrict__ b0,
                                                  const float* __restrict__ b1,
                                                  const float* __restrict__ b2,
                                                  float* __restrict__ un) {
  __shared__ bf16 inp_lds[64 * 40];    // 64 rows x BK=32 (+8 pad) bf16
  __shared__ bf16 h_lds[64 * 264];     // 64 rows x 256 (+8 pad) bf16
  __shared__ float bias_lds[512];
  __shared__ float part_lds[512];

  const int tid = threadIdx.x;
  const int wave = tid >> 6;
  const int lane = tid & 63;
  const int l16 = lane & 15;
  const int lq = lane >> 4;            // 0..3
  const long m0 = (long)blockIdx.x * 64;

  bias_lds[tid] = b0[tid];
  bias_lds[256 + tid] = b1[tid];

  f32x4 acc[4][4];
#pragma unroll
  for (int i = 0; i < 4; ++i)
#pragma unroll
    for (int j = 0; j < 4; ++j) acc[i][j] = (f32x4){0.f, 0.f, 0.f, 0.f};

  // input staging map: thread -> (row r, 8-float chunk q)
  const int r = tid >> 2;              // 0..63
  const int q = tid & 3;               // 0..3
  const float* gp = input + (m0 + r) * 512 + q * 8;
  float4 xa = *(const float4*)gp;
  float4 xb = *(const float4*)(gp + 4);

  // ---- layer 0: K=512, 16 iters of BK=32 -------------------------------
  for (int it = 0; it < 16; ++it) {
    __syncthreads();
    bf16x8 w;
    w[0] = (bf16)xa.x; w[1] = (bf16)xa.y; w[2] = (bf16)xa.z; w[3] = (bf16)xa.w;
    w[4] = (bf16)xb.x; w[5] = (bf16)xb.y; w[6] = (bf16)xb.z; w[7] = (bf16)xb.w;
    *(bf16x8*)&inp_lds[r * 40 + q * 8] = w;
    __syncthreads();
    if (it < 15) {
      gp += 32;
      xa = *(const float4*)gp;
      xb = *(const float4*)(gp + 4);
    }
    bf16x8 bfr[4];
#pragma unroll
    for (int nt = 0; nt < 4; ++nt)
      bfr[nt] = *(const bf16x8*)&inp_lds[(nt * 16 + l16) * 40 + lq * 8];
#pragma unroll
    for (int mt = 0; mt < 4; ++mt) {
      bf16x8 a = *(const bf16x8*)&W0f[(((wave * 4 + mt) * 16 + it) * 64 + lane) * 8];
#pragma unroll
      for (int nt = 0; nt < 4; ++nt) acc[mt][nt] = MFMA(a, bfr[nt], acc[mt][nt]);
    }
  }

  // epilogue 0: h0 = relu(D0 + b0) -> h_lds[m][n]
#pragma unroll
  for (int mt = 0; mt < 4; ++mt) {
    const int nbase = (wave * 4 + mt) * 16 + lq * 4;
    float bb[4];
#pragma unroll
    for (int g = 0; g < 4; ++g) bb[g] = bias_lds[nbase + g];
#pragma unroll
    for (int nt = 0; nt < 4; ++nt) {
      const int m = nt * 16 + l16;
      bf16x4 hv;
#pragma unroll
      for (int g = 0; g < 4; ++g) hv[g] = (bf16)fmaxf(acc[mt][nt][g] + bb[g], 0.f);
      *(bf16x4*)&h_lds[m * 264 + nbase] = hv;
    }
  }
  __syncthreads();

  // ---- layer 1: K=256, 8 ksteps ----------------------------------------
#pragma unroll
  for (int i = 0; i < 4; ++i)
#pragma unroll
    for (int j = 0; j < 4; ++j) acc[i][j] = (f32x4){0.f, 0.f, 0.f, 0.f};
  for (int ks = 0; ks < 8; ++ks) {
    bf16x8 bfr[4];
#pragma unroll
    for (int nt = 0; nt < 4; ++nt)
      bfr[nt] = *(const bf16x8*)&h_lds[(nt * 16 + l16) * 264 + ks * 32 + lq * 8];
#pragma unroll
    for (int mt = 0; mt < 4; ++mt) {
      bf16x8 a = *(const bf16x8*)&W1f[(((wave * 4 + mt) * 8 + ks) * 64 + lane) * 8];
#pragma unroll
      for (int nt = 0; nt < 4; ++nt) acc[mt][nt] = MFMA(a, bfr[nt], acc[mt][nt]);
    }
  }
  __syncthreads();   // everyone done reading h0 before overwrite

  // epilogue 1: h1 = relu(D1 + b1) -> h_lds[m][n]
#pragma unroll
  for (int mt = 0; mt < 4; ++mt) {
    const int nbase = (wave * 4 + mt) * 16 + lq * 4;
    float bb[4];
#pragma unroll
    for (int g = 0; g < 4; ++g) bb[g] = bias_lds[256 + nbase + g];
#pragma unroll
    for (int nt = 0; nt < 4; ++nt) {
      const int m = nt * 16 + l16;
      bf16x4 hv;
#pragma unroll
      for (int g = 0; g < 4; ++g) hv[g] = (bf16)fmaxf(acc[mt][nt][g] + bb[g], 0.f);
      *(bf16x4*)&h_lds[m * 264 + nbase] = hv;
    }
  }
  __syncthreads();

  // ---- layer 2: K=256 split across waves (2 ksteps each) ----------------
  f32x4 acc2[4];
#pragma unroll
  for (int i = 0; i < 4; ++i) acc2[i] = (f32x4){0.f, 0.f, 0.f, 0.f};
#pragma unroll
  for (int s = 0; s < 2; ++s) {
    const int ks = wave * 2 + s;
    bf16x8 a = *(const bf16x8*)&W2f[(ks * 64 + lane) * 8];
#pragma unroll
    for (int nt = 0; nt < 4; ++nt) {
      bf16x8 b = *(const bf16x8*)&h_lds[(nt * 16 + l16) * 264 + ks * 32 + lq * 8];
      acc2[nt] = MFMA(a, b, acc2[nt]);
    }
  }
  // valid rows c=0,1 live in regs 0,1 of lanes with lq==0
  if (lane < 16) {
#pragma unroll
    for (int nt = 0; nt < 4; ++nt) {
      part_lds[((wave * 4 + nt) * 16 + lane) * 2 + 0] = acc2[nt][0];
      part_lds[((wave * 4 + nt) * 16 + lane) * 2 + 1] = acc2[nt][1];
    }
  }
  __syncthreads();
  if (tid < 128) {
    const int mloc = tid >> 1, c = tid & 1;
    const int nt = mloc >> 4, l = mloc & 15;
    float s = b2[c];
#pragma unroll
    for (int w2 = 0; w2 < 4; ++w2) s += part_lds[((w2 * 4 + nt) * 16 + l) * 2 + c];
    un[(m0 + mloc) * 2 + c] = s;
  }
}

// ---------------------------------------------------------------------------
// relation MLP + pairwise pre-sum: bsum[b][s] = sum_p bp3[b, p, bit_i(s)+bit_j(s)]
// ---------------------------------------------------------------------------
__global__ __launch_bounds__(128) void k_bsum(const float* __restrict__ ctx,
                                              const float* __restrict__ R0,
                                              const float* __restrict__ r0,
                                              const float* __restrict__ R1,
                                              const float* __restrict__ r1,
                                              float* __restrict__ bsum) {
  __shared__ float ctx_l[105], R0_l[320], r0_l[64], R1_l[192], r1_l[3];
  __shared__ float h2[21 * 65];        // +1 pad col to dodge bank conflicts
  __shared__ float bp[63];
  const int t = threadIdx.x;
  const int b = blockIdx.x;
  if (t < 105) ctx_l[t] = ctx[b * 105 + t];
  for (int i = t; i < 320; i += 128) R0_l[i] = R0[i];
  if (t < 64) r0_l[t] = r0[t];
  for (int i = t; i < 192; i += 128) R1_l[i] = R1[i];
  if (t < 3) r1_l[t] = r1[t];
  __syncthreads();
  for (int idx = t; idx < 1344; idx += 128) {
    int p = idx >> 6, u = idx & 63;
    float a = r0_l[u];
#pragma unroll
    for (int x = 0; x < 5; ++x) a += ctx_l[p * 5 + x] * R0_l[x * 64 + u];
    h2[p * 65 + u] = fmaxf(a, 0.f);
  }
  __syncthreads();
  if (t < 63) {
    int p = t / 3, y = t - p * 3;
    float a = r1_l[y];
    for (int u = 0; u < 64; ++u) a += h2[p * 65 + u] * R1_l[u * 3 + y];
    bp[t] = a;
  }
  __syncthreads();
  // state s = t; entity i bit = (s >> (6-i)) & 1 (entity 0 most significant)
  float a = 0.f;
  int pi = 0;
#pragma unroll
  for (int i = 0; i < 7; ++i)
#pragma unroll
    for (int j = i + 1; j < 7; ++j) {
      int bi = (t >> (6 - i)) & 1, bj = (t >> (6 - j)) & 1;
      a += bp[pi * 3 + bi + bj];
      ++pi;
    }
  bsum[b * 128 + t] = a;
}

// ---------------------------------------------------------------------------
// joint + marginals: one block per (n,b); thread t = state s.
// ---------------------------------------------------------------------------
__global__ __launch_bounds__(128) void k_joint(const float* __restrict__ un,
                                               const float* __restrict__ bsum,
                                               float* __restrict__ out_marg,
                                               float* __restrict__ out_joint) {
  __shared__ float u_l[14];
  __shared__ float wred[16];   // [wave][8]: 0=tot, 1+q = sum over lane-bit q set, 7=max
  const int t = threadIdx.x;
  const int blk = blockIdx.x;
  const int n = blk & 31, b = blk >> 5;
  const long row = (long)n * 512 + b;
  if (t < 14) u_l[t] = un[row * 14 + t];
  __syncthreads();
  float j = bsum[b * 128 + t];
#pragma unroll
  for (int i = 0; i < 7; ++i) j += u_l[i * 2 + ((t >> (6 - i)) & 1)];
  const int w = t >> 6, lane = t & 63;
  float m = j;
#pragma unroll
  for (int o = 32; o; o >>= 1) m = fmaxf(m, __shfl_xor(m, o, 64));
  if (lane == 0) wred[w * 8 + 7] = m;
  __syncthreads();
  m = fmaxf(wred[7], wred[15]);
  float e = __expf(j - m);
  float tot = e;
#pragma unroll
  for (int o = 32; o; o >>= 1) tot += __shfl_xor(tot, o, 64);
  float s1q[6];
#pragma unroll
  for (int qb = 0; qb < 6; ++qb) {
    float v = ((lane >> qb) & 1) ? e : 0.f;
#pragma unroll
    for (int o = 32; o; o >>= 1) v += __shfl_xor(v, o, 64);
    s1q[qb] = v;
  }
  if (lane == 0) {
    wred[w * 8 + 0] = tot;
#pragma unroll
    for (int qb = 0; qb < 6; ++qb) wred[w * 8 + 1 + qb] = s1q[qb];
  }
  __syncthreads();
  const float T = wred[0] + wred[8];
  const float lT = __logf(T);
  out_joint[row * 128 + t] = (j - m) - lT;
  if (t < 7) {
    float s1, s0;
    if (t == 0) { s1 = wred[8]; s0 = wred[0]; }            // entity 0 = wave bit
    else {
      const int qb = 6 - t;                                // entity i -> lane bit 6-i
      s1 = wred[1 + qb] + wred[8 + 1 + qb];
      s0 = T - s1;
    }
    out_marg[row * 7 + t] = __logf(s1) - __logf(s0);
  }
}

// ---------------------------------------------------------------------------
extern "C" void kernel_launch(void* const* d_in, const int* in_sizes, int n_in,
                              void* d_out, int out_size, void* d_ws, size_t ws_size,
                              hipStream_t stream) {
  const float* input = (const float*)d_in[0];
  const float* ctx   = (const float*)d_in[1];
  // d_in[2]=lang_input, d_in[3]=num_markables: unused by the reference
  const float* W0 = (const float*)d_in[4];
  const float* b0 = (const float*)d_in[5];
  const float* W1 = (const float*)d_in[6];
  const float* b1 = (const float*)d_in[7];
  const float* W2 = (const float*)d_in[8];
  const float* b2 = (const float*)d_in[9];
  const float* R0 = (const float*)d_in[10];
  const float* r0 = (const float*)d_in[11];
  const float* R1 = (const float*)d_in[12];
  const float* r1 = (const float*)d_in[13];

  char* ws = (char*)d_ws;
  bf16* W0f  = (bf16*)(ws + 0);         // 262144 B
  bf16* W1f  = (bf16*)(ws + 262144);    // 131072 B
  bf16* W2f  = (bf16*)(ws + 393216);    //   8192 B
  float* un  = (float*)(ws + 401408);   // 917504 B
  float* bsm = (float*)(ws + 1318912);  // 262144 B

  float* out_marg = (float*)d_out;
  float* out_joint = out_marg + 114688;

  hipLaunchKernelGGL(k_prep, dim3(98), dim3(256), 0, stream, W0, W1, W2, W0f, W1f, W2f);
  hipLaunchKernelGGL(k_bsum, dim3(512), dim3(128), 0, stream, ctx, R0, r0, R1, r1, bsm);
  hipLaunchKernelGGL(k_unary, dim3(1792), dim3(256), 0, stream,
                     input, W0f, W1f, W2f, b0, b1, b2, un);
  hipLaunchKernelGGL(k_joint, dim3(16384), dim3(128), 0, stream, un, bsm, out_marg, out_joint);
}